// Round 8
// baseline (147.013 us; speedup 1.0000x reference)
//
#include <hip/hip_runtime.h>

// Problem constants (inputs: (32,64,32,32) fp32; embed: (64,1024) fp32)
#define N_PIX  32768   // B*H*W
#define C_DIM  64
#define K_EMB  1024
#define HW     1024    // H*W
#define P_TILE 8       // pixels per block

// d_out layout (float32, concatenated in return order):
//   quantized_out (B,C,H,W) | loss | encoding_indices | perplexity
#define OUT_Q_OFF    0
#define OUT_LOSS_OFF 2097152
#define OUT_IDX_OFF  2097153
#define OUT_PERP_OFF 2129921

// ws layout: lossPart[4096] floats @0 (plain stores; NO memset needed)

__device__ __forceinline__ unsigned long long pack_score(float d, int k) {
    unsigned int u = __float_as_uint(d);
    u = (u & 0x80000000u) ? ~u : (u | 0x80000000u);  // monotone map, negative-safe
    return ((unsigned long long)u << 32) | (unsigned int)k;
}

// k-major cooperative kernel, round-8 shape:
//   block = 128 threads (2 waves); each thread owns EIGHT k's: quad kL=4*tid
//   and quad kH=512+4*tid (both float4-coalesced). 8 pixels per block.
//   -> the 2 broadcast ds_read_b128 of x per c now feed 64 useful MACs (r7: 32),
//      halving DS-pipe occupancy per MAC and raising FMA issue density.
//   Software pipelining: e4 rotation 2 c ahead (~320cyc cover, r7-proven) and
//   xq ping-pong 1-2 c ahead (~160cyc > 120cyc DS latency).
//   Accs = 16 named float4 (AGPR-resident is FINE per r7: the r6 stall was
//   vmem latency, not AGPR penalty — this kernel is the discriminating test).
//   ||e||^2 fused; ||x||^2 dropped (constant under argmin). Per-block loss is
//   plain-stored to ws (kernel-boundary visibility), histogram moved to k_fin.
__global__ __launch_bounds__(128, 4) void k_main(
    const float* __restrict__ inp, const float* __restrict__ embed,
    float* __restrict__ lossPart, float* __restrict__ out_q,
    float* __restrict__ out_idx) {
    __shared__ float x_lds[C_DIM * P_TILE];           // 2 KB
    __shared__ unsigned long long red[2][P_TILE];
    __shared__ int ksel[P_TILE];
    __shared__ float lred[2];

    const int tid = threadIdx.x;                      // 0..127
    const int n0  = blockIdx.x * P_TILE;
    const int b   = n0 >> 10;
    const int hw0 = n0 & 1023;
    const float* __restrict__ xu = inp + b * (C_DIM * HW) + hw0;

    // stage x tile: 128 threads -> (c = tid>>1, one float4 half-row)
    {
        const int c  = tid >> 1;
        const int p4 = (tid & 1) * 4;
        *reinterpret_cast<float4*>(&x_lds[c * P_TILE + p4]) =
            *reinterpret_cast<const float4*>(xu + c * HW + p4);
    }
    __syncthreads();

    const int kL = tid * 4;            // low-half quad
    const int kH = 512 + tid * 4;      // high-half quad
    const float4* __restrict__ ebL = reinterpret_cast<const float4*>(embed) + tid;
    const float4* __restrict__ ebH = ebL + 128;   // +512 floats; row stride 256 float4

    float4 aL0={0,0,0,0},aL1={0,0,0,0},aL2={0,0,0,0},aL3={0,0,0,0};
    float4 aL4={0,0,0,0},aL5={0,0,0,0},aL6={0,0,0,0},aL7={0,0,0,0};
    float4 aH0={0,0,0,0},aH1={0,0,0,0},aH2={0,0,0,0},aH3={0,0,0,0};
    float4 aH4={0,0,0,0},aH5={0,0,0,0},aH6={0,0,0,0},aH7={0,0,0,0};
    float4 eeL={0,0,0,0}, eeH={0,0,0,0};

#define FMA8(i, xv, EL, EH) \
    aL##i.x = fmaf((xv), EL.x, aL##i.x); aL##i.y = fmaf((xv), EL.y, aL##i.y); \
    aL##i.z = fmaf((xv), EL.z, aL##i.z); aL##i.w = fmaf((xv), EL.w, aL##i.w); \
    aH##i.x = fmaf((xv), EH.x, aH##i.x); aH##i.y = fmaf((xv), EH.y, aH##i.y); \
    aH##i.z = fmaf((xv), EH.z, aH##i.z); aH##i.w = fmaf((xv), EH.w, aH##i.w);

#define BODY(EL, EH, A, B) { \
    eeL.x = fmaf(EL.x, EL.x, eeL.x); eeL.y = fmaf(EL.y, EL.y, eeL.y); \
    eeL.z = fmaf(EL.z, EL.z, eeL.z); eeL.w = fmaf(EL.w, EL.w, eeL.w); \
    eeH.x = fmaf(EH.x, EH.x, eeH.x); eeH.y = fmaf(EH.y, EH.y, eeH.y); \
    eeH.z = fmaf(EH.z, EH.z, eeH.z); eeH.w = fmaf(EH.w, EH.w, eeH.w); \
    FMA8(0, A.x, EL, EH) FMA8(1, A.y, EL, EH) \
    FMA8(2, A.z, EL, EH) FMA8(3, A.w, EL, EH) \
    FMA8(4, B.x, EL, EH) FMA8(5, B.y, EL, EH) \
    FMA8(6, B.z, EL, EH) FMA8(7, B.w, EL, EH) }

    float4 EL0 = ebL[0],   EH0 = ebH[0];
    float4 EL1 = ebL[256], EH1 = ebH[256];
    float4 XA = *reinterpret_cast<const float4*>(&x_lds[0]);
    float4 XB = *reinterpret_cast<const float4*>(&x_lds[4]);

#pragma unroll 1
    for (int c = 0; c < C_DIM; c += 2) {
        const int c2 = (c + 2) & 63, c3 = (c + 3) & 63;   // tail-safe wrap
        float4 NL0 = ebL[c2 * 256], NH0 = ebH[c2 * 256];
        float4 NL1 = ebL[c3 * 256], NH1 = ebH[c3 * 256];
        const float4 YA = *reinterpret_cast<const float4*>(&x_lds[(c + 1) * P_TILE + 0]);
        const float4 YB = *reinterpret_cast<const float4*>(&x_lds[(c + 1) * P_TILE + 4]);
        BODY(EL0, EH0, XA, XB)
        XA = *reinterpret_cast<const float4*>(&x_lds[c2 * P_TILE + 0]);
        XB = *reinterpret_cast<const float4*>(&x_lds[c2 * P_TILE + 4]);
        BODY(EL1, EH1, YA, YB)
        EL0 = NL0; EH0 = NH0; EL1 = NL1; EH1 = NH1;
    }
#undef BODY
#undef FMA8

    // per-pixel packed argmin: 8 candidate k's per thread, then 2-wave reduce
    const int wv = tid >> 6, ln = tid & 63;
#define RED_P(i) { \
        const float s0 = fmaf(-2.f, aL##i.x, eeL.x); \
        const float s1 = fmaf(-2.f, aL##i.y, eeL.y); \
        const float s2 = fmaf(-2.f, aL##i.z, eeL.z); \
        const float s3 = fmaf(-2.f, aL##i.w, eeL.w); \
        const float s4 = fmaf(-2.f, aH##i.x, eeH.x); \
        const float s5 = fmaf(-2.f, aH##i.y, eeH.y); \
        const float s6 = fmaf(-2.f, aH##i.z, eeH.z); \
        const float s7 = fmaf(-2.f, aH##i.w, eeH.w); \
        unsigned long long m = pack_score(s0, kL), t; \
        t = pack_score(s1, kL + 1); if (t < m) m = t; \
        t = pack_score(s2, kL + 2); if (t < m) m = t; \
        t = pack_score(s3, kL + 3); if (t < m) m = t; \
        t = pack_score(s4, kH);     if (t < m) m = t; \
        t = pack_score(s5, kH + 1); if (t < m) m = t; \
        t = pack_score(s6, kH + 2); if (t < m) m = t; \
        t = pack_score(s7, kH + 3); if (t < m) m = t; \
        for (int off = 32; off > 0; off >>= 1) { \
            unsigned long long o = __shfl_down(m, off, 64); \
            if (o < m) m = o; \
        } \
        if (ln == 0) red[wv][i] = m; }
    RED_P(0) RED_P(1) RED_P(2) RED_P(3)
    RED_P(4) RED_P(5) RED_P(6) RED_P(7)
#undef RED_P

    __syncthreads();
    if (tid < P_TILE) {
        unsigned long long m = red[0][tid];
        if (red[1][tid] < m) m = red[1][tid];
        const int k = (int)(unsigned int)(m & 0xFFFFFFFFull);
        ksel[tid] = k;
        out_idx[n0 + tid] = (float)k;
    }
    __syncthreads();

    // fused quantize + loss: 128 threads -> (c = tid>>1, 4 pixels); x from LDS
    {
        const int c  = tid >> 1;
        const int pb = (tid & 1) * 4;
        float ls = 0.f;
        float4 qv;
        float* qvp = &qv.x;
#pragma unroll
        for (int j = 0; j < 4; ++j) {
            const int k = ksel[pb + j];
            const float q  = embed[c * K_EMB + k];  // gather, L2-resident table
            const float xv = x_lds[c * P_TILE + pb + j];
            const float d  = q - xv;
            ls = fmaf(d, d, ls);
            qvp[j] = q;
        }
        *reinterpret_cast<float4*>(out_q + b * (C_DIM * HW) + c * HW + hw0 + pb) = qv;
        for (int off = 32; off > 0; off >>= 1) ls += __shfl_down(ls, off, 64);
        if (ln == 0) lred[wv] = ls;
    }
    __syncthreads();
    if (tid == 0) lossPart[blockIdx.x] = lred[0] + lred[1];  // plain store, no atomic
}

// finalize: histogram the 32768 indices (read back from out_idx), perplexity,
// and sum the 4096 per-block loss partials. One block; no pre-zeroed globals.
__global__ __launch_bounds__(1024) void k_fin(
    const float* __restrict__ out_idx_f, const float* __restrict__ lossPart,
    float* __restrict__ out_loss, float* __restrict__ out_perp) {
    __shared__ unsigned int hcnt[K_EMB];
    __shared__ float redP[16], redL[16];
    const int tid = threadIdx.x;  // 0..1023
    hcnt[tid] = 0;
    __syncthreads();
#pragma unroll
    for (int i = 0; i < 32; ++i) {
        const int k = (int)out_idx_f[tid + i * 1024];
        atomicAdd(&hcnt[k], 1u);
    }
    float ls = lossPart[tid] + lossPart[tid + 1024]
             + lossPart[tid + 2048] + lossPart[tid + 3072];
    __syncthreads();
    const float p = (float)hcnt[tid] * (1.0f / (float)N_PIX);
    float t = p * logf(p + 1e-10f);   // p==0 -> exactly 0, matches reference
    for (int off = 32; off > 0; off >>= 1) {
        t  += __shfl_down(t,  off, 64);
        ls += __shfl_down(ls, off, 64);
    }
    if ((tid & 63) == 0) { redP[tid >> 6] = t; redL[tid >> 6] = ls; }
    __syncthreads();
    if (tid == 0) {
        float s = 0.f, L = 0.f;
#pragma unroll
        for (int i = 0; i < 16; ++i) { s += redP[i]; L += redL[i]; }
        *out_perp = expf(-s);
        *out_loss = 0.25f * L * (1.0f / (float)(N_PIX * C_DIM));
    }
}

extern "C" void kernel_launch(void* const* d_in, const int* in_sizes, int n_in,
                              void* d_out, int out_size, void* d_ws, size_t ws_size,
                              hipStream_t stream) {
    const float* inp   = (const float*)d_in[0];
    const float* embed = (const float*)d_in[1];
    float* out = (float*)d_out;
    float* lossPart = (float*)d_ws;   // 4096 floats, written before read, no memset

    k_main<<<dim3(N_PIX / P_TILE), dim3(128), 0, stream>>>(
        inp, embed, lossPart, out + OUT_Q_OFF, out + OUT_IDX_OFF);
    k_fin<<<dim3(1), dim3(1024), 0, stream>>>(
        out + OUT_IDX_OFF, lossPart, out + OUT_LOSS_OFF, out + OUT_PERP_OFF);
}